// Round 8
// baseline (302.520 us; speedup 1.0000x reference)
//
#include <hip/hip_runtime.h>
#include <hip/hip_bf16.h>

// Problem constants
#define NBS   128
#define NF    182      // 20 text + 150 ocr/obj + 12 decode
#define NP    192      // padded N for MFMA tiling
#define DMODEL 768
#define NH    12
#define HDIM  64
#define SEQT  20
#define ROCR  150

typedef __attribute__((ext_vector_type(4))) float  f32x4;
typedef __attribute__((ext_vector_type(8))) short  s16x8;
using bf16 = __hip_bfloat16;

#define SB()    __builtin_amdgcn_sched_barrier(0)
#define BAR()   __builtin_amdgcn_s_barrier()

// global->LDS direct copy, 16B per lane. LDS dest linear in lane (base+lane*16).
__device__ __forceinline__ void gload_lds16(const void* g, void* l) {
    auto gp = (const __attribute__((address_space(1))) unsigned int*)((unsigned long long)g);
    auto lp = (__attribute__((address_space(3))) unsigned int*)(unsigned int)((unsigned long long)l);
    __builtin_amdgcn_global_load_lds(gp, lp, 16, 0, 0);
}

// ---------------------------------------------------------------------------
// Kernel 0: fp32 -> bf16 pre-convert. hs -> hsb. Wq|Wk|Wv -> Wb2 in per-head
// layout: Wb2 row R = h*192 + which*64 + r0  holds  W_which[h*64 + r0][:].
// ---------------------------------------------------------------------------
__global__ __launch_bounds__(256) void convert_bf16(
    const float* __restrict__ hs,
    const float* __restrict__ Wq, const float* __restrict__ Wk, const float* __restrict__ Wv,
    bf16* __restrict__ hsb, bf16* __restrict__ Wb2)
{
    const size_t HT = (size_t)NBS * NF * DMODEL / 8;        // 2,236,416
    const size_t WT = 3ull * DMODEL * DMODEL / 8;           // 221,184
    size_t i = (size_t)blockIdx.x * 256 + threadIdx.x;
    if (i >= HT + WT) return;
    const float* src; bf16* dst;
    if (i < HT) {
        size_t e = i * 8; src = hs + e; dst = hsb + e;
    } else {
        size_t e = (i - HT) * 8;                 // element idx in Wb2 (2304x768 row-major)
        int R = (int)(e / DMODEL), c = (int)(e % DMODEL);
        int h = R / 192, t2 = (R % 192) / 64, r0 = R % 64;
        src = (t2 == 0 ? Wq : t2 == 1 ? Wk : Wv) + (size_t)(h * 64 + r0) * DMODEL + c;
        dst = Wb2 + e;
    }
    float4 a = *reinterpret_cast<const float4*>(src);
    float4 b = *reinterpret_cast<const float4*>(src + 4);
    union { s16x8 v; bf16 h8[8]; } u;
    u.h8[0] = __float2bfloat16(a.x); u.h8[1] = __float2bfloat16(a.y);
    u.h8[2] = __float2bfloat16(a.z); u.h8[3] = __float2bfloat16(a.w);
    u.h8[4] = __float2bfloat16(b.x); u.h8[5] = __float2bfloat16(b.y);
    u.h8[6] = __float2bfloat16(b.z); u.h8[7] = __float2bfloat16(b.w);
    *reinterpret_cast<s16x8*>(dst) = u.v;
}

// ---------------------------------------------------------------------------
// Kernel 1: pack spatial adjacency (b,150,150,12) fp32 -> bitmask (b,12,150,3)
// ---------------------------------------------------------------------------
__global__ __launch_bounds__(256) void pack_adj(const float* __restrict__ adj,
                                                unsigned long long* __restrict__ bits)
{
    __shared__ float tile[ROCR * NH];       // 7.2 KB
    const int b = blockIdx.y, r = blockIdx.x;
    const int tid = threadIdx.x, lane = tid & 63, w = tid >> 6;
    const float* src = adj + ((size_t)b * ROCR + r) * (ROCR * NH);
    for (int i = tid; i < ROCR * NH; i += 256) tile[i] = src[i];
    __syncthreads();
    for (int c = w; c < NH * 3; c += 4) {
        int hh = c / 3, wd = c - hh * 3;
        int k = wd * 64 + lane;
        int j = k - SEQT;
        bool v = false;
        if (j >= 0 && j < ROCR) v = (tile[j * NH + hh] > 0.5f);
        unsigned long long m = __ballot(v);
        if (lane == 0) bits[(((size_t)b * NH + hh) * ROCR + r) * 3 + wd] = m;
    }
}

// ---------------------------------------------------------------------------
// Kernel 2: FUSED per-(b,h) QKV-projection + attention. 4 waves, 125KB LDS.
// Phase G: QKV[192x192] = hsb_panel[192x768] x Wb2_head^T[192x768], R5's
//   verified loop (BK=64, dbuf, counted vmcnt(12), chunk-XOR swizzle), wave
//   tile 96x96 (2x2 grid), acc 6x6 frags.
// Epilogue: acc+bias -> LDS: Q[192][64], K[192][64] (row-XOR swizzle), and
//   V transposed Vt[64][192] (keys>=182 zeroed -> NaN-safe).
// Phase A: verified attn body (bands of 16 q-rows, in-register softmax,
//   bitmask masking, P in per-wave LDS) reading Q/K/Vt from LDS.
// ---------------------------------------------------------------------------
#define QO   0
#define KO   24576
#define VTO  49152
#define PSH  98304
#define LWO  122880
#define AWO  127488

__global__ __launch_bounds__(256) void fused_qkv_attn(
    const bf16* __restrict__ hsb, const bf16* __restrict__ Wb2,
    const float* __restrict__ bq, const float* __restrict__ bk, const float* __restrict__ bv,
    const float* __restrict__ amask,
    const unsigned long long* __restrict__ bits,
    float* __restrict__ out)
{
    __shared__ char L[127520];
    const int tid  = threadIdx.x;
    const int lane = tid & 63;
    const int wid  = tid >> 6;
    const int wr = wid >> 1, wc = wid & 1;      // 2x2 wave grid, 96x96 each
    const int lm = lane & 15, lg = lane >> 4;

    // m204 XCD chunking (1536 = 8*192): 12 head-blocks of one b on one XCD.
    const int flat = blockIdx.x;
    const int wgid = (flat & 7) * 192 + (flat >> 3);
    const int b = wgid / NH, h = wgid - b * NH;

    float* obase = out + (size_t)b * NF * DMODEL + h * HDIM;

    // ---- masks + decode-row zeroing (independent of GEMM) ----
    if (wid == 0) {
        #pragma unroll
        for (int w = 0; w < 3; ++w) {
            int k = w * 64 + lane;
            bool v = (k < NF) && (amask[b * NF + k] == 0.0f);
            unsigned long long m = __ballot(v);
            if (lane == 0) ((unsigned long long*)(L + AWO))[w] = m;
        }
    }
    for (int i = tid; i < 12 * 64; i += 256)
        obase[(size_t)(170 + (i >> 6)) * DMODEL + (i & 63)] = 0.f;
    __syncthreads();
    if (tid < NP) {
        int r = tid;
        unsigned long long s0 = 0, s1 = 0, s2 = 0;
        const unsigned long long DEC = 0xFFFull << 42;      // keys 170..181
        if (r < SEQT) {
            s2 = DEC;
        } else if (r < SEQT + ROCR) {
            const unsigned long long* bp = bits + (((size_t)b * NH + h) * ROCR + (r - SEQT)) * 3;
            s0 = bp[0]; s1 = bp[1]; s2 = bp[2] | DEC;
        }
        unsigned long long* aw = (unsigned long long*)(L + AWO);
        unsigned long long* Lw = (unsigned long long*)(L + LWO);
        Lw[r * 3 + 0] = s0 & aw[0];
        Lw[r * 3 + 1] = s1 & aw[1];
        Lw[r * 3 + 2] = s2 & aw[2];
    }

    // ---- Phase G: GEMM ----
    const char* gA = (const char*)(hsb + (size_t)b * NF * DMODEL);   // 192 rows read (pad rows harmless)
    const char* gW = (const char*)(Wb2 + (size_t)h * 192 * DMODEL);

    f32x4 acc[6][6];
    #pragma unroll
    for (int i = 0; i < 6; ++i)
        #pragma unroll
        for (int j = 0; j < 6; ++j) acc[i][j] = (f32x4){0.f, 0.f, 0.f, 0.f};

    const int srow8 = tid >> 3, sch = tid & 7;

    auto ST = [&](int kt, int bsel) {
        char* dA = L + bsel * 49152;
        char* dW = dA + 24576;
        #pragma unroll
        for (int it = 0; it < 6; ++it) {
            int row = it * 32 + srow8;
            int lc = sch ^ (row & 7);
            size_t go = (size_t)row * 1536 + (size_t)kt * 128 + lc * 16;
            int o = row * 128 + sch * 16;
            gload_lds16(gA + go, dA + o);
            gload_lds16(gW + go, dW + o);
        }
    };
    auto CP = [&](int bsel) {
        const char* Ab = L + bsel * 49152;
        const char* Wp = Ab + 24576;
        #pragma unroll
        for (int kk = 0; kk < 2; ++kk) {
            int coff = ((kk * 4 + lg) ^ (lm & 7)) << 4;
            s16x8 af[6], bf6[6];
            #pragma unroll
            for (int mi = 0; mi < 6; ++mi)
                af[mi] = *reinterpret_cast<const s16x8*>(Ab + (96 * wr + 16 * mi + lm) * 128 + coff);
            #pragma unroll
            for (int ni = 0; ni < 6; ++ni)
                bf6[ni] = *reinterpret_cast<const s16x8*>(Wp + (96 * wc + 16 * ni + lm) * 128 + coff);
            #pragma unroll
            for (int mi = 0; mi < 6; ++mi)
                #pragma unroll
                for (int ni = 0; ni < 6; ++ni)
                    acc[mi][ni] = __builtin_amdgcn_mfma_f32_16x16x32_bf16(af[mi], bf6[ni], acc[mi][ni], 0, 0, 0);
        }
    };

    ST(0, 0);
    ST(1, 1);
    for (int t = 0; t < 12; ++t) {
        if (t < 11) { asm volatile("s_waitcnt vmcnt(12)" ::: "memory"); }
        else        { asm volatile("s_waitcnt vmcnt(0)"  ::: "memory"); }
        SB(); BAR(); SB();
        CP(t & 1);
        SB(); BAR();
        if (t + 2 < 12) ST(t + 2, t & 1);
    }

    // ---- epilogue: acc + bias -> Q/K/Vt LDS ----
    float bias6[6];
    #pragma unroll
    for (int ni = 0; ni < 6; ++ni) {
        int c = 96 * wc + 16 * ni + lm;
        int whichc = c >> 6, cc = c & 63;
        const float* bp = (whichc == 0) ? bq : (whichc == 1) ? bk : bv;
        bias6[ni] = bp[h * 64 + cc];
    }
    #pragma unroll
    for (int mi = 0; mi < 6; ++mi) {
        #pragma unroll
        for (int ni = 0; ni < 6; ++ni) {
            int c = 96 * wc + 16 * ni + lm;
            #pragma unroll
            for (int j = 0; j < 4; ++j) {
                int row = 96 * wr + 16 * mi + 4 * lg + j;
                bf16 hv = __float2bfloat16(acc[mi][ni][j] + bias6[ni]);
                unsigned short us = *reinterpret_cast<unsigned short*>(&hv);
                if (c < 128) {
                    int base = (c < 64) ? QO : KO;
                    int cc = c & 63;
                    *reinterpret_cast<unsigned short*>(L + base + row * 128 + ((2 * cc) ^ ((row & 7) << 4))) = us;
                } else if (row < NF) {
                    int d = c - 128;
                    *reinterpret_cast<unsigned short*>(L + VTO + d * 384 + ((2 * row) ^ ((d & 7) << 4))) = us;
                }
            }
        }
    }
    // zero Vt pad keys 182..191 (NaN containment)
    for (int i = tid; i < 64 * 10; i += 256) {
        int d = i / 10, k2 = NF + (i - d * 10);
        *reinterpret_cast<unsigned short*>(L + VTO + d * 384 + ((2 * k2) ^ ((d & 7) << 4))) = 0;
    }
    __syncthreads();

    // ---- Phase A: attention (verified body; Q/K/Vt from LDS) ----
    const unsigned long long* LwA = (const unsigned long long*)(L + LWO);
    char* Pw = L + PSH + wid * 6144;

    for (int band = wid; band < 11; band += 4) {
        const int q0 = band * 16;
        int qrow = q0 + lm;
        const char* qb = L + QO + qrow * 128;
        int sq = (qrow & 7) << 4;
        s16x8 qf0 = *reinterpret_cast<const s16x8*>(qb + ((lg * 16) ^ sq));
        s16x8 qf1 = *reinterpret_cast<const s16x8*>(qb + ((64 + lg * 16) ^ sq));

        f32x4 sacc[12];
        #pragma unroll
        for (int t = 0; t < 12; ++t) sacc[t] = (f32x4){0.f, 0.f, 0.f, 0.f};
        #pragma unroll
        for (int t = 0; t < 12; ++t) {
            int key = t * 16 + lm;
            const char* kb = L + KO + key * 128;
            int sw = (key & 7) << 4;
            s16x8 kf0 = *reinterpret_cast<const s16x8*>(kb + ((lg * 16) ^ sw));
            s16x8 kf1 = *reinterpret_cast<const s16x8*>(kb + ((64 + lg * 16) ^ sw));
            sacc[t] = __builtin_amdgcn_mfma_f32_16x16x32_bf16(qf0, kf0, sacc[t], 0, 0, 0);
            sacc[t] = __builtin_amdgcn_mfma_f32_16x16x32_bf16(qf1, kf1, sacc[t], 0, 0, 0);
        }

        float scl[4];
        #pragma unroll
        for (int j = 0; j < 4; ++j) {
            int row = q0 + lg * 4 + j;
            unsigned long long w0 = LwA[row * 3 + 0], w1 = LwA[row * 3 + 1], w2 = LwA[row * 3 + 2];
            float mx = -3.0e38f;
            #pragma unroll
            for (int t = 0; t < 12; ++t) {
                unsigned long long w = (t < 4) ? w0 : (t < 8) ? w1 : w2;
                int sh = ((t & 3) << 4) + lm;
                float s = sacc[t][j] * 0.125f;
                s = ((w >> sh) & 1ull) ? s : -3.0e38f;
                sacc[t][j] = s;
                mx = fmaxf(mx, s);
            }
            mx = fmaxf(mx, __shfl_xor(mx, 1));
            mx = fmaxf(mx, __shfl_xor(mx, 2));
            mx = fmaxf(mx, __shfl_xor(mx, 4));
            mx = fmaxf(mx, __shfl_xor(mx, 8));
            float sum = 0.f;
            #pragma unroll
            for (int t = 0; t < 12; ++t) {
                float e = (sacc[t][j] > -1.0e37f) ? __expf(sacc[t][j] - mx) : 0.f;
                sacc[t][j] = e;
                sum += e;
            }
            sum += __shfl_xor(sum, 1);
            sum += __shfl_xor(sum, 2);
            sum += __shfl_xor(sum, 4);
            sum += __shfl_xor(sum, 8);
            scl[j] = (mx > -1.0e37f) ? 1.0f / sum : 0.f;
        }

        #pragma unroll
        for (int j = 0; j < 4; ++j) {
            int prow = lg * 4 + j;
            int sw = (prow & 7) << 4;
            char* prb = Pw + prow * (NP * 2);
            #pragma unroll
            for (int t = 0; t < 12; ++t) {
                bf16 pv = __float2bfloat16(sacc[t][j] * scl[j]);
                *reinterpret_cast<unsigned short*>(prb + (((t * 16 + lm) * 2) ^ sw)) =
                    *reinterpret_cast<unsigned short*>(&pv);
            }
        }
        asm volatile("s_waitcnt lgkmcnt(0)" ::: "memory");
        __builtin_amdgcn_sched_barrier(0);

        f32x4 oacc[4];
        #pragma unroll
        for (int t = 0; t < 4; ++t) oacc[t] = (f32x4){0.f, 0.f, 0.f, 0.f};
        int psw = (lm & 7) << 4;
        #pragma unroll
        for (int ks = 0; ks < 6; ++ks) {
            s16x8 pf = *reinterpret_cast<const s16x8*>(Pw + lm * (NP * 2) + ((ks * 64 + lg * 16) ^ psw));
            #pragma unroll
            for (int t = 0; t < 4; ++t) {
                int d = t * 16 + lm;
                s16x8 vf = *reinterpret_cast<const s16x8*>(L + VTO + d * 384 + ((ks * 64 + lg * 16) ^ ((d & 7) << 4)));
                oacc[t] = __builtin_amdgcn_mfma_f32_16x16x32_bf16(pf, vf, oacc[t], 0, 0, 0);
            }
        }
        #pragma unroll
        for (int j = 0; j < 4; ++j) {
            int row = q0 + lg * 4 + j;
            if (row < 170) {
                #pragma unroll
                for (int t = 0; t < 4; ++t)
                    obase[(size_t)row * DMODEL + t * 16 + lm] = oacc[t][j];
            }
        }
    }
}

// ---------------------------------------------------------------------------
extern "C" void kernel_launch(void* const* d_in, const int* in_sizes, int n_in,
                              void* d_out, int out_size, void* d_ws, size_t ws_size,
                              hipStream_t stream)
{
    const float* hs    = (const float*)d_in[0];
    const float* amask = (const float*)d_in[1];
    const float* adj   = (const float*)d_in[2];
    const float* Wq    = (const float*)d_in[3];
    const float* bq    = (const float*)d_in[4];
    const float* Wk    = (const float*)d_in[5];
    const float* bk    = (const float*)d_in[6];
    const float* Wv    = (const float*)d_in[7];
    const float* bv    = (const float*)d_in[8];
    float* out = (float*)d_out;

    // workspace: Wb2 (3.54MB) | bits (5.53MB) | hsb (35.8MB + slack for pad-row reads)
    char* ws = (char*)d_ws;
    bf16* Wb2 = (bf16*)ws;                                       // 2304*768*2 = 3,538,944
    unsigned long long* bits = (unsigned long long*)(ws + 3538944);
    bf16* hsb = (bf16*)(ws + 3538944 + 5529600);                 // 23296*768*2 = 35,782,656

    const int cvt_blocks = (int)(((size_t)NBS * NF * DMODEL / 8 + 3ull * DMODEL * DMODEL / 8 + 255) / 256);
    convert_bf16<<<cvt_blocks, 256, 0, stream>>>(hs, Wq, Wk, Wv, hsb, Wb2);
    pack_adj<<<dim3(ROCR, NBS), 256, 0, stream>>>(adj, bits);
    fused_qkv_attn<<<dim3(NBS * NH), 256, 0, stream>>>(hsb, Wb2, bq, bk, bv, amask, bits, out);
}

// Round 9
// 220.948 us; speedup vs baseline: 1.3692x; 1.3692x over previous
//
#include <hip/hip_runtime.h>
#include <hip/hip_bf16.h>

// Problem constants
#define NBS   128
#define NF    182      // 20 text + 150 ocr/obj + 12 decode
#define NP    192      // padded N for MFMA tiling
#define DMODEL 768
#define NH    12
#define HDIM  64
#define SEQT  20
#define ROCR  150

typedef __attribute__((ext_vector_type(4))) float  f32x4;
typedef __attribute__((ext_vector_type(8))) short  s16x8;
using bf16 = __hip_bfloat16;

#define SB()    __builtin_amdgcn_sched_barrier(0)
#define BAR()   __builtin_amdgcn_s_barrier()

// global->LDS direct copy, 16B per lane. LDS dest linear in lane (base+lane*16).
__device__ __forceinline__ void gload_lds16(const void* g, void* l) {
    auto gp = (const __attribute__((address_space(1))) unsigned int*)((unsigned long long)g);
    auto lp = (__attribute__((address_space(3))) unsigned int*)(unsigned int)((unsigned long long)l);
    __builtin_amdgcn_global_load_lds(gp, lp, 16, 0, 0);
}

// ---------------------------------------------------------------------------
// Kernel 0: fp32 -> bf16 pre-convert. hs -> hsb. Wq|Wk|Wv -> Wb2 in per-head
// layout: Wb2 row R = h*192 + which*64 + r0  holds  W_which[h*64 + r0][:].
// ---------------------------------------------------------------------------
__global__ __launch_bounds__(256) void convert_bf16(
    const float* __restrict__ hs,
    const float* __restrict__ Wq, const float* __restrict__ Wk, const float* __restrict__ Wv,
    bf16* __restrict__ hsb, bf16* __restrict__ Wb2)
{
    const size_t HT = (size_t)NBS * NF * DMODEL / 8;        // 2,236,416
    const size_t WT = 3ull * DMODEL * DMODEL / 8;           // 221,184
    size_t i = (size_t)blockIdx.x * 256 + threadIdx.x;
    if (i >= HT + WT) return;
    const float* src; bf16* dst;
    if (i < HT) {
        size_t e = i * 8; src = hs + e; dst = hsb + e;
    } else {
        size_t e = (i - HT) * 8;                 // element idx in Wb2 (2304x768 row-major)
        int R = (int)(e / DMODEL), c = (int)(e % DMODEL);
        int h = R / 192, t2 = (R % 192) / 64, r0 = R % 64;
        src = (t2 == 0 ? Wq : t2 == 1 ? Wk : Wv) + (size_t)(h * 64 + r0) * DMODEL + c;
        dst = Wb2 + e;
    }
    float4 a = *reinterpret_cast<const float4*>(src);
    float4 b = *reinterpret_cast<const float4*>(src + 4);
    union { s16x8 v; bf16 h8[8]; } u;
    u.h8[0] = __float2bfloat16(a.x); u.h8[1] = __float2bfloat16(a.y);
    u.h8[2] = __float2bfloat16(a.z); u.h8[3] = __float2bfloat16(a.w);
    u.h8[4] = __float2bfloat16(b.x); u.h8[5] = __float2bfloat16(b.y);
    u.h8[6] = __float2bfloat16(b.z); u.h8[7] = __float2bfloat16(b.w);
    *reinterpret_cast<s16x8*>(dst) = u.v;
}

// ---------------------------------------------------------------------------
// Kernel 1: pack spatial adjacency (b,150,150,12) fp32 -> bitmask (b,12,150,3)
// ---------------------------------------------------------------------------
__global__ __launch_bounds__(256) void pack_adj(const float* __restrict__ adj,
                                                unsigned long long* __restrict__ bits)
{
    __shared__ float tile[ROCR * NH];       // 7.2 KB
    const int b = blockIdx.y, r = blockIdx.x;
    const int tid = threadIdx.x, lane = tid & 63, w = tid >> 6;
    const float* src = adj + ((size_t)b * ROCR + r) * (ROCR * NH);
    for (int i = tid; i < ROCR * NH; i += 256) tile[i] = src[i];
    __syncthreads();
    for (int c = w; c < NH * 3; c += 4) {
        int hh = c / 3, wd = c - hh * 3;
        int k = wd * 64 + lane;
        int j = k - SEQT;
        bool v = false;
        if (j >= 0 && j < ROCR) v = (tile[j * NH + hh] > 0.5f);
        unsigned long long m = __ballot(v);
        if (lane == 0) bits[(((size_t)b * NH + hh) * ROCR + r) * 3 + wd] = m;
    }
}

// ---------------------------------------------------------------------------
// Kernel 2: FUSED per-(b,h) QKV-projection + attention. 4 waves, 76.6KB LDS
// -> 2 blocks/CU (block A's attn overlaps block B's GEMM).
// LDS region plan (aliased across phases):
//   [0..49152)     staging dbuf (BK=32: A 12KB + W 12KB per tile)
//                  -> after GEMM: K[192][64] swz @0, Vt[64][192] swz @24576
//   [49152..73728) Q[192][64] swz  -> after Q-preload: P (4 waves x 6144)
//   [73728..78360) Lw bitmasks + aw
// GEMM: 24 K-tiles, counted vmcnt(6), chunk-XOR swizzle (R7, conflicts=0),
// setprio around MFMA cluster. Attn: R8's verified body.
// ---------------------------------------------------------------------------
#define KO2   0
#define VTO2  24576
#define QO2   49152
#define PO2   49152
#define LWO2  73728
#define AWO2  78336

__global__ __launch_bounds__(256, 2) void fused_qkv_attn(
    const bf16* __restrict__ hsb, const bf16* __restrict__ Wb2,
    const float* __restrict__ bq, const float* __restrict__ bk, const float* __restrict__ bv,
    const float* __restrict__ amask,
    const unsigned long long* __restrict__ bits,
    float* __restrict__ out)
{
    __shared__ char L[78368];
    const int tid  = threadIdx.x;
    const int lane = tid & 63;
    const int wid  = tid >> 6;
    const int wr = wid >> 1, wc = wid & 1;      // 2x2 wave grid, 96x96 each
    const int lm = lane & 15, lg = lane >> 4;

    // m204 XCD chunking (1536 = 8*192): 12 head-blocks of one b on one XCD.
    const int flat = blockIdx.x;
    const int wgid = (flat & 7) * 192 + (flat >> 3);
    const int b = wgid / NH, h = wgid - b * NH;

    float* obase = out + (size_t)b * NF * DMODEL + h * HDIM;

    // ---- masks + decode-row zeroing (independent of GEMM) ----
    if (wid == 0) {
        #pragma unroll
        for (int w = 0; w < 3; ++w) {
            int k = w * 64 + lane;
            bool v = (k < NF) && (amask[b * NF + k] == 0.0f);
            unsigned long long m = __ballot(v);
            if (lane == 0) ((unsigned long long*)(L + AWO2))[w] = m;
        }
    }
    for (int i = tid; i < 12 * 64; i += 256)
        obase[(size_t)(170 + (i >> 6)) * DMODEL + (i & 63)] = 0.f;
    __syncthreads();
    if (tid < NP) {
        int r = tid;
        unsigned long long s0 = 0, s1 = 0, s2 = 0;
        const unsigned long long DEC = 0xFFFull << 42;      // keys 170..181
        if (r < SEQT) {
            s2 = DEC;
        } else if (r < SEQT + ROCR) {
            const unsigned long long* bp = bits + (((size_t)b * NH + h) * ROCR + (r - SEQT)) * 3;
            s0 = bp[0]; s1 = bp[1]; s2 = bp[2] | DEC;
        }
        unsigned long long* aw = (unsigned long long*)(L + AWO2);
        unsigned long long* Lw = (unsigned long long*)(L + LWO2);
        Lw[r * 3 + 0] = s0 & aw[0];
        Lw[r * 3 + 1] = s1 & aw[1];
        Lw[r * 3 + 2] = s2 & aw[2];
    }

    // ---- Phase G: GEMM (BK=32, dbuf, counted vmcnt(6)) ----
    const char* gA = (const char*)(hsb + (size_t)b * NF * DMODEL);   // 192 rows (pad rows harmless)
    const char* gW = (const char*)(Wb2 + (size_t)h * 192 * DMODEL);

    f32x4 acc[6][6];
    #pragma unroll
    for (int i = 0; i < 6; ++i)
        #pragma unroll
        for (int j = 0; j < 6; ++j) acc[i][j] = (f32x4){0.f, 0.f, 0.f, 0.f};

    const int srow4 = tid >> 2, sch4 = tid & 3;

    auto ST = [&](int kt, int bsel) {
        char* dA = L + bsel * 24576;
        char* dW = dA + 12288;
        #pragma unroll
        for (int it = 0; it < 3; ++it) {
            int row = it * 64 + srow4;
            int lc = sch4 ^ ((row >> 1) & 3);
            size_t go = (size_t)row * 1536 + (size_t)kt * 64 + lc * 16;
            int o = row * 64 + sch4 * 16;
            gload_lds16(gA + go, dA + o);
            gload_lds16(gW + go, dW + o);
        }
    };
    auto CP = [&](int bsel) {
        const char* Ab = L + bsel * 24576;
        const char* Wp = Ab + 12288;
        s16x8 af[6], bf6[6];
        #pragma unroll
        for (int mi = 0; mi < 6; ++mi) {
            int r = 96 * wr + 16 * mi + lm;
            af[mi] = *reinterpret_cast<const s16x8*>(Ab + r * 64 + ((lg ^ ((r >> 1) & 3)) << 4));
        }
        #pragma unroll
        for (int ni = 0; ni < 6; ++ni) {
            int r = 96 * wc + 16 * ni + lm;
            bf6[ni] = *reinterpret_cast<const s16x8*>(Wp + r * 64 + ((lg ^ ((r >> 1) & 3)) << 4));
        }
        __builtin_amdgcn_s_setprio(1);
        #pragma unroll
        for (int mi = 0; mi < 6; ++mi)
            #pragma unroll
            for (int ni = 0; ni < 6; ++ni)
                acc[mi][ni] = __builtin_amdgcn_mfma_f32_16x16x32_bf16(af[mi], bf6[ni], acc[mi][ni], 0, 0, 0);
        __builtin_amdgcn_s_setprio(0);
    };

    ST(0, 0);
    ST(1, 1);
    for (int t = 0; t < 24; ++t) {
        if (t < 23) { asm volatile("s_waitcnt vmcnt(6)" ::: "memory"); }
        else        { asm volatile("s_waitcnt vmcnt(0)" ::: "memory"); }
        SB(); BAR(); SB();
        CP(t & 1);
        SB(); BAR();
        if (t + 2 < 24) ST(t + 2, t & 1);
    }
    BAR();   // all CP reads done before epilogue overwrites staging region

    // ---- epilogue: acc + bias -> Q / K / Vt LDS ----
    float bias6[6];
    #pragma unroll
    for (int ni = 0; ni < 6; ++ni) {
        int c = 96 * wc + 16 * ni + lm;
        int whichc = c >> 6, cc = c & 63;
        const float* bp = (whichc == 0) ? bq : (whichc == 1) ? bk : bv;
        bias6[ni] = bp[h * 64 + cc];
    }
    #pragma unroll
    for (int mi = 0; mi < 6; ++mi) {
        #pragma unroll
        for (int ni = 0; ni < 6; ++ni) {
            int c = 96 * wc + 16 * ni + lm;
            #pragma unroll
            for (int j = 0; j < 4; ++j) {
                int row = 96 * wr + 16 * mi + 4 * lg + j;
                bf16 hv = __float2bfloat16(acc[mi][ni][j] + bias6[ni]);
                unsigned short us = *reinterpret_cast<unsigned short*>(&hv);
                if (c < 64) {
                    *reinterpret_cast<unsigned short*>(L + QO2 + row * 128 + ((2 * c) ^ ((row & 7) << 4))) = us;
                } else if (c < 128) {
                    int cc = c - 64;
                    *reinterpret_cast<unsigned short*>(L + KO2 + row * 128 + ((2 * cc) ^ ((row & 7) << 4))) = us;
                } else if (row < NF) {
                    int d = c - 128;
                    *reinterpret_cast<unsigned short*>(L + VTO2 + d * 384 + ((2 * row) ^ ((d & 7) << 4))) = us;
                }
            }
        }
    }
    // zero Vt pad keys 182..191 (NaN containment)
    for (int i = tid; i < 64 * 10; i += 256) {
        int d = i / 10, k2 = NF + (i - d * 10);
        *reinterpret_cast<unsigned short*>(L + VTO2 + d * 384 + ((2 * k2) ^ ((d & 7) << 4))) = 0;
    }
    __syncthreads();

    // ---- Q-preload: each wave pulls its 3 bands' Q-fragments to registers,
    //      then the Q region is recycled as the P buffer ----
    s16x8 qf[3][2];
    #pragma unroll
    for (int bi = 0; bi < 3; ++bi) {
        int band = wid + 4 * bi;
        int qrow = ((band < 11) ? band : 0) * 16 + lm;      // safe dummy for band>=11
        const char* qb = L + QO2 + qrow * 128;
        int sq = (qrow & 7) << 4;
        qf[bi][0] = *reinterpret_cast<const s16x8*>(qb + ((lg * 16) ^ sq));
        qf[bi][1] = *reinterpret_cast<const s16x8*>(qb + ((64 + lg * 16) ^ sq));
    }
    __syncthreads();    // drains lgkm: all Q reads complete before P overwrites

    // ---- Phase A: attention ----
    const unsigned long long* LwA = (const unsigned long long*)(L + LWO2);
    char* Pw = L + PO2 + wid * 6144;

    #pragma unroll
    for (int bi = 0; bi < 3; ++bi) {
        const int band = wid + 4 * bi;
        if (band >= 11) continue;
        const int q0 = band * 16;

        f32x4 sacc[12];
        #pragma unroll
        for (int t = 0; t < 12; ++t) sacc[t] = (f32x4){0.f, 0.f, 0.f, 0.f};
        #pragma unroll
        for (int t = 0; t < 12; ++t) {
            int key = t * 16 + lm;
            const char* kb = L + KO2 + key * 128;
            int sw = (key & 7) << 4;
            s16x8 kf0 = *reinterpret_cast<const s16x8*>(kb + ((lg * 16) ^ sw));
            s16x8 kf1 = *reinterpret_cast<const s16x8*>(kb + ((64 + lg * 16) ^ sw));
            sacc[t] = __builtin_amdgcn_mfma_f32_16x16x32_bf16(qf[bi][0], kf0, sacc[t], 0, 0, 0);
            sacc[t] = __builtin_amdgcn_mfma_f32_16x16x32_bf16(qf[bi][1], kf1, sacc[t], 0, 0, 0);
        }

        float scl[4];
        #pragma unroll
        for (int j = 0; j < 4; ++j) {
            int row = q0 + lg * 4 + j;
            unsigned long long w0 = LwA[row * 3 + 0], w1 = LwA[row * 3 + 1], w2 = LwA[row * 3 + 2];
            float mx = -3.0e38f;
            #pragma unroll
            for (int t = 0; t < 12; ++t) {
                unsigned long long w = (t < 4) ? w0 : (t < 8) ? w1 : w2;
                int sh = ((t & 3) << 4) + lm;
                float s = sacc[t][j] * 0.125f;
                s = ((w >> sh) & 1ull) ? s : -3.0e38f;
                sacc[t][j] = s;
                mx = fmaxf(mx, s);
            }
            mx = fmaxf(mx, __shfl_xor(mx, 1));
            mx = fmaxf(mx, __shfl_xor(mx, 2));
            mx = fmaxf(mx, __shfl_xor(mx, 4));
            mx = fmaxf(mx, __shfl_xor(mx, 8));
            float sum = 0.f;
            #pragma unroll
            for (int t = 0; t < 12; ++t) {
                float e = (sacc[t][j] > -1.0e37f) ? __expf(sacc[t][j] - mx) : 0.f;
                sacc[t][j] = e;
                sum += e;
            }
            sum += __shfl_xor(sum, 1);
            sum += __shfl_xor(sum, 2);
            sum += __shfl_xor(sum, 4);
            sum += __shfl_xor(sum, 8);
            scl[j] = (mx > -1.0e37f) ? 1.0f / sum : 0.f;
        }

        #pragma unroll
        for (int j = 0; j < 4; ++j) {
            int prow = lg * 4 + j;
            int sw = (prow & 7) << 4;
            char* prb = Pw + prow * 384;
            #pragma unroll
            for (int t = 0; t < 12; ++t) {
                bf16 pv = __float2bfloat16(sacc[t][j] * scl[j]);
                *reinterpret_cast<unsigned short*>(prb + (((t * 16 + lm) * 2) ^ sw)) =
                    *reinterpret_cast<unsigned short*>(&pv);
            }
        }
        asm volatile("s_waitcnt lgkmcnt(0)" ::: "memory");
        __builtin_amdgcn_sched_barrier(0);

        f32x4 oacc[4];
        #pragma unroll
        for (int t = 0; t < 4; ++t) oacc[t] = (f32x4){0.f, 0.f, 0.f, 0.f};
        int psw = (lm & 7) << 4;
        #pragma unroll
        for (int ks = 0; ks < 6; ++ks) {
            s16x8 pf = *reinterpret_cast<const s16x8*>(Pw + lm * 384 + ((ks * 64 + lg * 16) ^ psw));
            #pragma unroll
            for (int t = 0; t < 4; ++t) {
                int d = t * 16 + lm;
                s16x8 vf = *reinterpret_cast<const s16x8*>(L + VTO2 + d * 384 + ((ks * 64 + lg * 16) ^ ((d & 7) << 4)));
                oacc[t] = __builtin_amdgcn_mfma_f32_16x16x32_bf16(pf, vf, oacc[t], 0, 0, 0);
            }
        }
        #pragma unroll
        for (int j = 0; j < 4; ++j) {
            int row = q0 + lg * 4 + j;
            if (row < 170) {
                #pragma unroll
                for (int t = 0; t < 4; ++t)
                    obase[(size_t)row * DMODEL + t * 16 + lm] = oacc[t][j];
            }
        }
    }
}

// ---------------------------------------------------------------------------
extern "C" void kernel_launch(void* const* d_in, const int* in_sizes, int n_in,
                              void* d_out, int out_size, void* d_ws, size_t ws_size,
                              hipStream_t stream)
{
    const float* hs    = (const float*)d_in[0];
    const float* amask = (const float*)d_in[1];
    const float* adj   = (const float*)d_in[2];
    const float* Wq    = (const float*)d_in[3];
    const float* bq    = (const float*)d_in[4];
    const float* Wk    = (const float*)d_in[5];
    const float* bk    = (const float*)d_in[6];
    const float* Wv    = (const float*)d_in[7];
    const float* bv    = (const float*)d_in[8];
    float* out = (float*)d_out;

    // workspace: Wb2 (3.54MB) | bits (5.53MB) | hsb (35.8MB + pad-row slack)
    char* ws = (char*)d_ws;
    bf16* Wb2 = (bf16*)ws;                                       // 2304*768*2 = 3,538,944
    unsigned long long* bits = (unsigned long long*)(ws + 3538944);
    bf16* hsb = (bf16*)(ws + 3538944 + 5529600);                 // 23296*768*2 = 35,782,656

    const int cvt_blocks = (int)(((size_t)NBS * NF * DMODEL / 8 + 3ull * DMODEL * DMODEL / 8 + 255) / 256);
    convert_bf16<<<cvt_blocks, 256, 0, stream>>>(hs, Wq, Wk, Wv, hsb, Wb2);
    pack_adj<<<dim3(ROCR, NBS), 256, 0, stream>>>(adj, bits);
    fused_qkv_attn<<<dim3(NBS * NH), 256, 0, stream>>>(hsb, Wb2, bq, bk, bv, amask, bits, out);
}